// Round 1
// baseline (198.915 us; speedup 1.0000x reference)
//
#include <hip/hip_runtime.h>

#define NF   16
#define C    8
#define NB   4
#define NPIX (512*512)

// sums grid: GRIDX blocks per batch, 256 threads, wave w owns features 4w..4w+3
#define GRIDX  256
#define CHUNK  (NPIX / GRIDX)        // 1024 pixels per block
#define SITERS (CHUNK / (64 * 4))    // 4 iterations, compile-time

// dist grid: DGRIDX blocks per batch, each thread owns exactly 4 pixels
#define DGRIDX 256                   // 256*256*4 == NPIX

// ws float layout:
//   [0,512)     sums[b][c*16+f]
//   [512,544)   counts[b*8+c]
//   [544,1056)  means[b][f*8+c]   (transposed for conflict-free LDS gather)
//   [1056,1060) invsum[b]
#define WS_CNT   512
#define WS_MEAN  544
#define WS_INV   1056
#define WS_TOTAL 1060

__global__ void init_kernel(float* __restrict__ ws, float* __restrict__ out) {
    int t = blockIdx.x * blockDim.x + threadIdx.x;
    if (t < WS_TOTAL) ws[t] = 0.0f;
    if (t == 0) out[0] = 0.0f;
}

// Register-accumulation sums: wave w owns features 4w..4w+3 (no LDS atomics).
// Compile-time trip count (SITERS) so the compiler can pipeline the loads.
// Tail: shfl_xor butterfly (all lanes hold totals), then 32 lanes commit one
// atomic each in a single memory instruction instead of 32 serial atomics.
__global__ __launch_bounds__(256, 4) void sums_kernel(const float* __restrict__ pred,
                                                      const int* __restrict__ tgt,
                                                      float* __restrict__ ws) {
    const int tid  = threadIdx.x;
    const int lane = tid & 63;
    const int wave = tid >> 6;          // 0..3
    const int b    = blockIdx.y;
    const int f0   = wave * 4;          // this wave's features: f0..f0+3

    float acc[4][8];
#pragma unroll
    for (int i = 0; i < 4; ++i)
#pragma unroll
        for (int c = 0; c < 8; ++c) acc[i][c] = 0.0f;
    float cnt[8];
#pragma unroll
    for (int c = 0; c < 8; ++c) cnt[c] = 0.0f;

    const float* predb = pred + (size_t)b * NF * NPIX;
    const int*   tgtb  = tgt  + (size_t)b * NPIX;
    const int start = blockIdx.x * CHUNK;

#pragma unroll
    for (int it = 0; it < SITERS; ++it) {
        const int base = start + it * 256 + lane * 4;
        int4 lab = *(const int4*)(tgtb + base);
        float4 p[4];
#pragma unroll
        for (int fi = 0; fi < 4; ++fi)
            p[fi] = *(const float4*)(predb + (f0 + fi) * NPIX + base);

        float m0[8], m1[8], m2[8], m3[8];
#pragma unroll
        for (int c = 0; c < 8; ++c) {
            m0[c] = (lab.x == c) ? 1.0f : 0.0f;
            m1[c] = (lab.y == c) ? 1.0f : 0.0f;
            m2[c] = (lab.z == c) ? 1.0f : 0.0f;
            m3[c] = (lab.w == c) ? 1.0f : 0.0f;
        }
        if (wave == 0) {
#pragma unroll
            for (int c = 0; c < 8; ++c)
                cnt[c] += m0[c] + m1[c] + m2[c] + m3[c];
        }
#pragma unroll
        for (int fi = 0; fi < 4; ++fi) {
#pragma unroll
            for (int c = 0; c < 8; ++c)
                acc[fi][c] += m0[c] * p[fi].x + m1[c] * p[fi].y
                            + m2[c] * p[fi].z + m3[c] * p[fi].w;
        }
    }

    // xor-butterfly: every lane ends with the full 64-lane total of each value
#pragma unroll
    for (int off = 32; off > 0; off >>= 1) {
#pragma unroll
        for (int fi = 0; fi < 4; ++fi)
#pragma unroll
            for (int c = 0; c < 8; ++c)
                acc[fi][c] += __shfl_xor(acc[fi][c], off);
    }
    if (wave == 0) {
#pragma unroll
        for (int off = 32; off > 0; off >>= 1)
#pragma unroll
            for (int c = 0; c < 8; ++c)
                cnt[c] += __shfl_xor(cnt[c], off);
    }

    // parallel commit: lane l (<32) owns (fi = l>>3, c = l&7); static-index select
    {
        const int l5 = lane & 31;
        const int fi = l5 >> 3;
        const int c  = l5 & 7;
        float v = 0.0f;
#pragma unroll
        for (int fj = 0; fj < 4; ++fj)
#pragma unroll
            for (int cj = 0; cj < 8; ++cj)
                v = (l5 == fj * 8 + cj) ? acc[fj][cj] : v;
        if (lane < 32) {
            float* gsum = ws + b * (C * NF);
            atomicAdd(&gsum[c * NF + (f0 + fi)], v);
        }
        if (wave == 0) {
            float cv = 0.0f;
#pragma unroll
            for (int cj = 0; cj < 8; ++cj)
                cv = (lane == 32 + cj) ? cnt[cj] : cv;
            if (lane >= 32 && lane < 40)
                atomicAdd(&ws[WS_CNT + b * C + (lane - 32)], cv);
        }
    }
}

__global__ void means_kernel(float* __restrict__ ws) {
    int t = threadIdx.x;               // 512 threads: b=t/128, c=(t/16)%8, f=t%16
    int b = t >> 7;
    int r = t & 127;
    int c = r >> 4;
    int f = r & 15;
    float cnt = ws[WS_CNT + b * C + c];
    ws[WS_MEAN + b * 128 + f * C + c] = ws[b * 128 + c * NF + f] / cnt;
    if (f == 0) atomicAdd(&ws[WS_INV + b], 1.0f / cnt);
}

// One compile-time iteration: each thread owns exactly 4 pixels.
__global__ __launch_bounds__(256, 4) void dist_kernel(const float* __restrict__ pred,
                                                      const int* __restrict__ tgt,
                                                      const float* __restrict__ ws,
                                                      float* __restrict__ out) {
    __shared__ float s_means[C * NF];
    __shared__ float s_red[4];
    const int tid = threadIdx.x;
    const int b   = blockIdx.y;
    if (tid < C * NF) s_means[tid] = ws[WS_MEAN + b * 128 + tid];
    const float invs = ws[WS_INV + b];
    __syncthreads();

    const float* predb = pred + (size_t)b * NF * NPIX;
    const int*   tgtb  = tgt  + (size_t)b * NPIX;

    const int base = (blockIdx.x * 256 + tid) * 4;
    int4 lab = *(const int4*)(tgtb + base);
    float s0 = 0.f, s1 = 0.f, s2 = 0.f, s3 = 0.f;
#pragma unroll
    for (int f = 0; f < NF; ++f) {
        float4 p = *(const float4*)(predb + f * NPIX + base);
        float d0 = s_means[f * C + lab.x] - p.x;
        float d1 = s_means[f * C + lab.y] - p.y;
        float d2 = s_means[f * C + lab.z] - p.z;
        float d3 = s_means[f * C + lab.w] - p.w;
        s0 += d0 * d0; s1 += d1 * d1; s2 += d2 * d2; s3 += d3 * d3;
    }
    float t0 = fminf(fmaxf(sqrtf(s0) - 0.5f, 0.0f), 100000.0f);
    float t1 = fminf(fmaxf(sqrtf(s1) - 0.5f, 0.0f), 100000.0f);
    float t2 = fminf(fmaxf(sqrtf(s2) - 0.5f, 0.0f), 100000.0f);
    float t3 = fminf(fmaxf(sqrtf(s3) - 0.5f, 0.0f), 100000.0f);
    float acc = t0 * t0 + t1 * t1 + t2 * t2 + t3 * t3;

#pragma unroll
    for (int off = 32; off > 0; off >>= 1) acc += __shfl_down(acc, off);
    const int lane = tid & 63, wave = tid >> 6;
    if (lane == 0) s_red[wave] = acc;
    __syncthreads();
    if (tid == 0) {
        float tot = s_red[0] + s_red[1] + s_red[2] + s_red[3];
        atomicAdd(out, tot * invs * 0.125f);
    }
}

extern "C" void kernel_launch(void* const* d_in, const int* in_sizes, int n_in,
                              void* d_out, int out_size, void* d_ws, size_t ws_size,
                              hipStream_t stream) {
    const float* pred = (const float*)d_in[0];
    const int*   tgt  = (const int*)d_in[1];
    float* out = (float*)d_out;
    float* ws  = (float*)d_ws;

    init_kernel<<<dim3((WS_TOTAL + 255) / 256), dim3(256), 0, stream>>>(ws, out);
    sums_kernel<<<dim3(GRIDX, NB), dim3(256), 0, stream>>>(pred, tgt, ws);
    means_kernel<<<dim3(1), dim3(512), 0, stream>>>(ws);
    dist_kernel<<<dim3(DGRIDX, NB), dim3(256), 0, stream>>>(pred, tgt, ws, out);
}

// Round 2
// 198.649 us; speedup vs baseline: 1.0013x; 1.0013x over previous
//
#include <hip/hip_runtime.h>

#define NF   16
#define C    8
#define NB   4
#define NPIX (512*512)

// sums grid: GRIDX blocks per batch, 256 threads, wave w owns features 4w..4w+3
#define GRIDX  512
#define CHUNK  (NPIX / GRIDX)        // 512 pixels per block
#define SITERS (CHUNK / (64 * 4))    // 2 iterations, compile-time, fully unrolled

// dist grid: DGRIDX blocks per batch, each thread owns exactly 4 pixels
#define DGRIDX 256                   // 256*256*4 == NPIX

// ws float layout:
//   [0,512)     sums[b][c*16+f]
//   [512,544)   counts[b*8+c]
//   [544,1056)  means[b][f*8+c]   (transposed for conflict-free LDS gather)
//   [1056,1060) invsum[b]
#define WS_CNT   512
#define WS_MEAN  544
#define WS_INV   1056
#define WS_TOTAL 1060

__global__ void init_kernel(float* __restrict__ ws, float* __restrict__ out) {
    int t = blockIdx.x * blockDim.x + threadIdx.x;
    if (t < WS_TOTAL) ws[t] = 0.0f;
    if (t == 0) out[0] = 0.0f;
}

// Register-accumulation sums. Structure: issue ALL loads first (straight-line,
// ~10 KB in flight per wave), then compute pixel-by-pixel (masks live only 8
// regs at a time). NO launch_bounds min-waves arg: (256,4) capped VGPR at 64
// and caused 118 MB of scratch spill traffic in round 1.
__global__ __launch_bounds__(256) void sums_kernel(const float* __restrict__ pred,
                                                   const int* __restrict__ tgt,
                                                   float* __restrict__ ws) {
    const int tid  = threadIdx.x;
    const int lane = tid & 63;
    const int wave = tid >> 6;          // 0..3
    const int b    = blockIdx.y;
    const int f0   = wave * 4;          // this wave's features: f0..f0+3

    const float* predb = pred + (size_t)b * NF * NPIX;
    const int*   tgtb  = tgt  + (size_t)b * NPIX;
    const int start = blockIdx.x * CHUNK;

    // ---- phase 1: issue every load back-to-back (2 int4 + 8 float4) ----
    int4  lab[SITERS];
    float4 p[SITERS][4];
#pragma unroll
    for (int it = 0; it < SITERS; ++it) {
        const int base = start + it * 256 + lane * 4;
        lab[it] = *(const int4*)(tgtb + base);
#pragma unroll
        for (int fi = 0; fi < 4; ++fi)
            p[it][fi] = *(const float4*)(predb + (f0 + fi) * NPIX + base);
    }

    // ---- phase 2: compute; masks recomputed per pixel (8 live regs) ----
    float acc[4][8];
#pragma unroll
    for (int i = 0; i < 4; ++i)
#pragma unroll
        for (int c = 0; c < 8; ++c) acc[i][c] = 0.0f;
    float cnt[8];
#pragma unroll
    for (int c = 0; c < 8; ++c) cnt[c] = 0.0f;

#pragma unroll
    for (int it = 0; it < SITERS; ++it) {
        const int labs[4] = { lab[it].x, lab[it].y, lab[it].z, lab[it].w };
#pragma unroll
        for (int px = 0; px < 4; ++px) {
            const int lv = labs[px];
            float m[8];
#pragma unroll
            for (int c = 0; c < 8; ++c) m[c] = (lv == c) ? 1.0f : 0.0f;
            if (wave == 0) {
#pragma unroll
                for (int c = 0; c < 8; ++c) cnt[c] += m[c];
            }
#pragma unroll
            for (int fi = 0; fi < 4; ++fi) {
                const float pv = (px == 0) ? p[it][fi].x :
                                 (px == 1) ? p[it][fi].y :
                                 (px == 2) ? p[it][fi].z : p[it][fi].w;
#pragma unroll
                for (int c = 0; c < 8; ++c) acc[fi][c] += m[c] * pv;
            }
        }
    }

    // xor-butterfly: every lane ends with the full 64-lane total of each value
#pragma unroll
    for (int off = 32; off > 0; off >>= 1) {
#pragma unroll
        for (int fi = 0; fi < 4; ++fi)
#pragma unroll
            for (int c = 0; c < 8; ++c)
                acc[fi][c] += __shfl_xor(acc[fi][c], off);
    }
    if (wave == 0) {
#pragma unroll
        for (int off = 32; off > 0; off >>= 1)
#pragma unroll
            for (int c = 0; c < 8; ++c)
                cnt[c] += __shfl_xor(cnt[c], off);
    }

    // parallel commit: lane l (<32) owns (fi = l>>3, c = l&7); static-index select
    {
        const int l5 = lane & 31;
        const int fi = l5 >> 3;
        const int c  = l5 & 7;
        float v = 0.0f;
#pragma unroll
        for (int fj = 0; fj < 4; ++fj)
#pragma unroll
            for (int cj = 0; cj < 8; ++cj)
                v = (l5 == fj * 8 + cj) ? acc[fj][cj] : v;
        if (lane < 32) {
            float* gsum = ws + b * (C * NF);
            atomicAdd(&gsum[c * NF + (f0 + fi)], v);
        }
        if (wave == 0) {
            float cv = 0.0f;
#pragma unroll
            for (int cj = 0; cj < 8; ++cj)
                cv = (lane == 32 + cj) ? cnt[cj] : cv;
            if (lane >= 32 && lane < 40)
                atomicAdd(&ws[WS_CNT + b * C + (lane - 32)], cv);
        }
    }
}

__global__ void means_kernel(float* __restrict__ ws) {
    int t = threadIdx.x;               // 512 threads: b=t/128, c=(t/16)%8, f=t%16
    int b = t >> 7;
    int r = t & 127;
    int c = r >> 4;
    int f = r & 15;
    float cnt = ws[WS_CNT + b * C + c];
    ws[WS_MEAN + b * 128 + f * C + c] = ws[b * 128 + c * NF + f] / cnt;
    if (f == 0) atomicAdd(&ws[WS_INV + b], 1.0f / cnt);
}

// One compile-time iteration: each thread owns exactly 4 pixels.
// Loads issued first (1 int4 + 16 float4 ~= 17 KB/wave in flight), then compute.
__global__ __launch_bounds__(256) void dist_kernel(const float* __restrict__ pred,
                                                   const int* __restrict__ tgt,
                                                   const float* __restrict__ ws,
                                                   float* __restrict__ out) {
    __shared__ float s_means[C * NF];
    __shared__ float s_red[4];
    const int tid = threadIdx.x;
    const int b   = blockIdx.y;
    if (tid < C * NF) s_means[tid] = ws[WS_MEAN + b * 128 + tid];
    const float invs = ws[WS_INV + b];
    __syncthreads();

    const float* predb = pred + (size_t)b * NF * NPIX;
    const int*   tgtb  = tgt  + (size_t)b * NPIX;

    const int base = (blockIdx.x * 256 + tid) * 4;
    int4 lab = *(const int4*)(tgtb + base);
    float4 p[NF];
#pragma unroll
    for (int f = 0; f < NF; ++f)
        p[f] = *(const float4*)(predb + f * NPIX + base);

    float s0 = 0.f, s1 = 0.f, s2 = 0.f, s3 = 0.f;
#pragma unroll
    for (int f = 0; f < NF; ++f) {
        float d0 = s_means[f * C + lab.x] - p[f].x;
        float d1 = s_means[f * C + lab.y] - p[f].y;
        float d2 = s_means[f * C + lab.z] - p[f].z;
        float d3 = s_means[f * C + lab.w] - p[f].w;
        s0 += d0 * d0; s1 += d1 * d1; s2 += d2 * d2; s3 += d3 * d3;
    }
    float t0 = fminf(fmaxf(sqrtf(s0) - 0.5f, 0.0f), 100000.0f);
    float t1 = fminf(fmaxf(sqrtf(s1) - 0.5f, 0.0f), 100000.0f);
    float t2 = fminf(fmaxf(sqrtf(s2) - 0.5f, 0.0f), 100000.0f);
    float t3 = fminf(fmaxf(sqrtf(s3) - 0.5f, 0.0f), 100000.0f);
    float acc = t0 * t0 + t1 * t1 + t2 * t2 + t3 * t3;

#pragma unroll
    for (int off = 32; off > 0; off >>= 1) acc += __shfl_down(acc, off);
    const int lane = tid & 63, wave = tid >> 6;
    if (lane == 0) s_red[wave] = acc;
    __syncthreads();
    if (tid == 0) {
        float tot = s_red[0] + s_red[1] + s_red[2] + s_red[3];
        atomicAdd(out, tot * invs * 0.125f);
    }
}

extern "C" void kernel_launch(void* const* d_in, const int* in_sizes, int n_in,
                              void* d_out, int out_size, void* d_ws, size_t ws_size,
                              hipStream_t stream) {
    const float* pred = (const float*)d_in[0];
    const int*   tgt  = (const int*)d_in[1];
    float* out = (float*)d_out;
    float* ws  = (float*)d_ws;

    init_kernel<<<dim3((WS_TOTAL + 255) / 256), dim3(256), 0, stream>>>(ws, out);
    sums_kernel<<<dim3(GRIDX, NB), dim3(256), 0, stream>>>(pred, tgt, ws);
    means_kernel<<<dim3(1), dim3(512), 0, stream>>>(ws);
    dist_kernel<<<dim3(DGRIDX, NB), dim3(256), 0, stream>>>(pred, tgt, ws, out);
}

// Round 4
// 119.006 us; speedup vs baseline: 1.6715x; 1.6692x over previous
//
#include <hip/hip_runtime.h>

#define NF   16
#define C    8
#define NB   4
#define NPIX (512*512)

// sums: SG blocks per batch, 256 threads; wave w owns features 4w..4w+3
#define SG      128
#define SCHUNK  (NPIX / SG)          // 2048 pixels per block
#define SITERS  (SCHUNK / (64 * 4))  // 8 iterations per wave

// dist: DG blocks per batch, 256 threads, 4 px per thread per iteration
#define DG      128
#define DCHUNK  (NPIX / DG)          // 2048 pixels per block
#define DITERS  (DCHUNK / (256 * 4)) // 2 iterations

// ws float layout (no atomics anywhere; every slot written before read):
//   PSUM: [b][blk][128]  fc = f*8+c   NB*SG*128 = 65536 floats
//   PCNT: [b][blk][8]                 NB*SG*8   = 4096
//   MEAN: [b][128]       fc = f*8+c   512
//   INV:  [b]                         4
//   POUT: [b][DG]                     512
#define WS_PSUM 0
#define WS_PCNT (NB * SG * 128)
#define WS_MEAN (WS_PCNT + NB * SG * 8)
#define WS_INV  (WS_MEAN + NB * 128)
#define WS_POUT (WS_INV + NB)

// Register-accumulation partial sums. Commit via PLAIN COALESCED STORES to a
// per-block slot — rounds 0-2 were bound by same-line fp atomics ping-ponging
// across XCDs (~600ns per op, serialized per address).
__global__ __launch_bounds__(256) void sums_kernel(const float* __restrict__ pred,
                                                   const int* __restrict__ tgt,
                                                   float* __restrict__ ws) {
    const int tid  = threadIdx.x;
    const int lane = tid & 63;
    const int wave = tid >> 6;          // 0..3
    const int b    = blockIdx.y;
    const int f0   = wave * 4;          // this wave's features: f0..f0+3

    const float* predb = pred + (size_t)b * NF * NPIX;
    const int*   tgtb  = tgt  + (size_t)b * NPIX;
    const int start = blockIdx.x * SCHUNK;

    float acc[4][8];
#pragma unroll
    for (int i = 0; i < 4; ++i)
#pragma unroll
        for (int c = 0; c < 8; ++c) acc[i][c] = 0.0f;
    float cnt[8];
#pragma unroll
    for (int c = 0; c < 8; ++c) cnt[c] = 0.0f;

#pragma unroll 2
    for (int it = 0; it < SITERS; ++it) {
        const int base = start + it * 256 + lane * 4;
        int4 lab = *(const int4*)(tgtb + base);
        float4 p[4];
#pragma unroll
        for (int fi = 0; fi < 4; ++fi)
            p[fi] = *(const float4*)(predb + (f0 + fi) * NPIX + base);

        const int labs[4] = { lab.x, lab.y, lab.z, lab.w };
#pragma unroll
        for (int px = 0; px < 4; ++px) {
            const int lv = labs[px];
            float m[8];
#pragma unroll
            for (int c = 0; c < 8; ++c) m[c] = (lv == c) ? 1.0f : 0.0f;
            if (wave == 0) {
#pragma unroll
                for (int c = 0; c < 8; ++c) cnt[c] += m[c];
            }
#pragma unroll
            for (int fi = 0; fi < 4; ++fi) {
                const float pv = (px == 0) ? p[fi].x :
                                 (px == 1) ? p[fi].y :
                                 (px == 2) ? p[fi].z : p[fi].w;
#pragma unroll
                for (int c = 0; c < 8; ++c) acc[fi][c] += m[c] * pv;
            }
        }
    }

    // xor-butterfly: every lane ends with the full 64-lane total of each value
#pragma unroll
    for (int off = 32; off > 0; off >>= 1) {
#pragma unroll
        for (int fi = 0; fi < 4; ++fi)
#pragma unroll
            for (int c = 0; c < 8; ++c)
                acc[fi][c] += __shfl_xor(acc[fi][c], off);
    }
    if (wave == 0) {
#pragma unroll
        for (int off = 32; off > 0; off >>= 1)
#pragma unroll
            for (int c = 0; c < 8; ++c)
                cnt[c] += __shfl_xor(cnt[c], off);
    }

    // commit: lane l<32 owns (fi=l>>3, c=l&7); fc = (f0+fi)*8+c = f0*8+l
    // -> each wave stores 32 CONTIGUOUS floats (one coalesced 128B store)
    {
        float v = 0.0f;
#pragma unroll
        for (int fj = 0; fj < 4; ++fj)
#pragma unroll
            for (int cj = 0; cj < 8; ++cj)
                v = (lane == fj * 8 + cj) ? acc[fj][cj] : v;
        if (lane < 32)
            ws[WS_PSUM + ((size_t)(b * SG + blockIdx.x)) * 128 + f0 * 8 + lane] = v;
        if (wave == 0) {
            float cv = 0.0f;
#pragma unroll
            for (int cj = 0; cj < 8; ++cj)
                cv = (lane == 32 + cj) ? cnt[cj] : cv;
            if (lane >= 32 && lane < 40)
                ws[WS_PCNT + (b * SG + blockIdx.x) * 8 + (lane - 32)] = cv;
        }
    }
}

// One block, 512 threads: reduce partials, compute means (transposed) + invsum.
__global__ void means_kernel(float* __restrict__ ws) {
    __shared__ float scnt[32];
    const int t = threadIdx.x;
    if (t < 32) {
        const int b = t >> 3, c = t & 7;
        float s = 0.0f;
        for (int blk = 0; blk < SG; ++blk)
            s += ws[WS_PCNT + (b * SG + blk) * 8 + c];
        scnt[t] = s;
    }
    __syncthreads();
    const int b = t >> 7, fc = t & 127, c = fc & 7;
    float s = 0.0f;
    for (int blk = 0; blk < SG; ++blk)
        s += ws[WS_PSUM + ((size_t)(b * SG + blk)) * 128 + fc];
    ws[WS_MEAN + b * 128 + fc] = s / scnt[b * 8 + c];
    if (fc == 0) {
        float iv = 0.0f;
#pragma unroll
        for (int c8 = 0; c8 < 8; ++c8) iv += 1.0f / scnt[b * 8 + c8];
        ws[WS_INV + b] = iv;
    }
}

// Per-block partial of the distance sum, committed via plain store to pout.
__global__ __launch_bounds__(256) void dist_kernel(const float* __restrict__ pred,
                                                   const int* __restrict__ tgt,
                                                   const float* __restrict__ ws,
                                                   float* __restrict__ pout) {
    __shared__ float s_means[C * NF];
    __shared__ float s_red[4];
    const int tid = threadIdx.x;
    const int b   = blockIdx.y;
    if (tid < C * NF) s_means[tid] = ws[WS_MEAN + b * 128 + tid];
    const float invs = ws[WS_INV + b];
    __syncthreads();

    const float* predb = pred + (size_t)b * NF * NPIX;
    const int*   tgtb  = tgt  + (size_t)b * NPIX;

    float acc = 0.0f;
#pragma unroll
    for (int it = 0; it < DITERS; ++it) {
        const int base = blockIdx.x * DCHUNK + it * 1024 + tid * 4;
        int4 lab = *(const int4*)(tgtb + base);
        float s0 = 0.f, s1 = 0.f, s2 = 0.f, s3 = 0.f;
#pragma unroll
        for (int f = 0; f < NF; ++f) {
            float4 p = *(const float4*)(predb + f * NPIX + base);
            float d0 = s_means[f * C + lab.x] - p.x;
            float d1 = s_means[f * C + lab.y] - p.y;
            float d2 = s_means[f * C + lab.z] - p.z;
            float d3 = s_means[f * C + lab.w] - p.w;
            s0 += d0 * d0; s1 += d1 * d1; s2 += d2 * d2; s3 += d3 * d3;
        }
        float t0 = fminf(fmaxf(sqrtf(s0) - 0.5f, 0.0f), 100000.0f);
        float t1 = fminf(fmaxf(sqrtf(s1) - 0.5f, 0.0f), 100000.0f);
        float t2 = fminf(fmaxf(sqrtf(s2) - 0.5f, 0.0f), 100000.0f);
        float t3 = fminf(fmaxf(sqrtf(s3) - 0.5f, 0.0f), 100000.0f);
        acc += t0 * t0 + t1 * t1 + t2 * t2 + t3 * t3;
    }
#pragma unroll
    for (int off = 32; off > 0; off >>= 1) acc += __shfl_down(acc, off);
    const int lane = tid & 63, wave = tid >> 6;
    if (lane == 0) s_red[wave] = acc;
    __syncthreads();
    if (tid == 0) {
        float tot = s_red[0] + s_red[1] + s_red[2] + s_red[3];
        pout[b * DG + blockIdx.x] = tot * invs * 0.125f;
    }
}

// One block, 512 threads: sum the 512 dist partials, plain store to out.
__global__ void final_kernel(const float* __restrict__ pout, float* __restrict__ out) {
    __shared__ float sr[8];
    const int t = threadIdx.x;
    float v = pout[t];
#pragma unroll
    for (int off = 32; off > 0; off >>= 1) v += __shfl_xor(v, off);
    if ((t & 63) == 0) sr[t >> 6] = v;
    __syncthreads();
    if (t == 0) {
        float s = 0.0f;
#pragma unroll
        for (int i = 0; i < 8; ++i) s += sr[i];
        out[0] = s;
    }
}

extern "C" void kernel_launch(void* const* d_in, const int* in_sizes, int n_in,
                              void* d_out, int out_size, void* d_ws, size_t ws_size,
                              hipStream_t stream) {
    const float* pred = (const float*)d_in[0];
    const int*   tgt  = (const int*)d_in[1];
    float* out = (float*)d_out;
    float* ws  = (float*)d_ws;

    sums_kernel<<<dim3(SG, NB), dim3(256), 0, stream>>>(pred, tgt, ws);
    means_kernel<<<dim3(1), dim3(512), 0, stream>>>(ws);
    dist_kernel<<<dim3(DG, NB), dim3(256), 0, stream>>>(pred, tgt, ws, ws + WS_POUT);
    final_kernel<<<dim3(1), dim3(512), 0, stream>>>(ws + WS_POUT, out);
}

// Round 5
// 116.723 us; speedup vs baseline: 1.7042x; 1.0196x over previous
//
#include <hip/hip_runtime.h>

#define NF   16
#define C    8
#define NB   4
#define NPIX (512*512)

// sums: SG blocks per batch, 256 threads; wave w owns features 4w..4w+3
#define SG      256
#define SCHUNK  (NPIX / SG)          // 1024 pixels per block
#define SITERS  (SCHUNK / (64 * 4))  // 4 iterations per wave

// dist: DG blocks per batch, 256 threads, 4 px per thread, single iteration
#define DG      256
#define DCHUNK  (NPIX / DG)          // 1024 pixels per block

// ws float layout (no atomics anywhere; every slot written before read):
//   PSUM: [b][blk][128]  fc = f*8+c   NB*SG*128 = 131072 floats
//   PCNT: [b][blk][8]                 NB*SG*8   = 8192
//   MEAN: [b][128]       fc = f*8+c   512
//   INV:  [b]                         4
//   POUT: [b][DG]                     1024
#define WS_PSUM 0
#define WS_PCNT (NB * SG * 128)
#define WS_MEAN (WS_PCNT + NB * SG * 8)
#define WS_INV  (WS_MEAN + NB * 128)
#define WS_POUT (WS_INV + NB)

// Register-accumulation partial sums; plain coalesced stores (no atomics —
// rounds 0-2 were bound by same-line fp atomics serializing across XCDs).
__global__ __launch_bounds__(256) void sums_kernel(const float* __restrict__ pred,
                                                   const int* __restrict__ tgt,
                                                   float* __restrict__ ws) {
    const int tid  = threadIdx.x;
    const int lane = tid & 63;
    const int wave = tid >> 6;          // 0..3
    const int b    = blockIdx.y;
    const int f0   = wave * 4;          // this wave's features: f0..f0+3

    const float* predb = pred + (size_t)b * NF * NPIX;
    const int*   tgtb  = tgt  + (size_t)b * NPIX;
    const int start = blockIdx.x * SCHUNK;

    float acc[4][8];
#pragma unroll
    for (int i = 0; i < 4; ++i)
#pragma unroll
        for (int c = 0; c < 8; ++c) acc[i][c] = 0.0f;
    float cnt[8];
#pragma unroll
    for (int c = 0; c < 8; ++c) cnt[c] = 0.0f;

#pragma unroll
    for (int it = 0; it < SITERS; ++it) {
        const int base = start + it * 256 + lane * 4;
        int4 lab = *(const int4*)(tgtb + base);
        float4 p[4];
#pragma unroll
        for (int fi = 0; fi < 4; ++fi)
            p[fi] = *(const float4*)(predb + (f0 + fi) * NPIX + base);

        const int labs[4] = { lab.x, lab.y, lab.z, lab.w };
#pragma unroll
        for (int px = 0; px < 4; ++px) {
            const int lv = labs[px];
            float m[8];
#pragma unroll
            for (int c = 0; c < 8; ++c) m[c] = (lv == c) ? 1.0f : 0.0f;
            if (wave == 0) {
#pragma unroll
                for (int c = 0; c < 8; ++c) cnt[c] += m[c];
            }
#pragma unroll
            for (int fi = 0; fi < 4; ++fi) {
                const float pv = (px == 0) ? p[fi].x :
                                 (px == 1) ? p[fi].y :
                                 (px == 2) ? p[fi].z : p[fi].w;
#pragma unroll
                for (int c = 0; c < 8; ++c) acc[fi][c] += m[c] * pv;
            }
        }
    }

    // xor-butterfly: every lane ends with the full 64-lane total
#pragma unroll
    for (int off = 32; off > 0; off >>= 1) {
#pragma unroll
        for (int fi = 0; fi < 4; ++fi)
#pragma unroll
            for (int c = 0; c < 8; ++c)
                acc[fi][c] += __shfl_xor(acc[fi][c], off);
    }
    if (wave == 0) {
#pragma unroll
        for (int off = 32; off > 0; off >>= 1)
#pragma unroll
            for (int c = 0; c < 8; ++c)
                cnt[c] += __shfl_xor(cnt[c], off);
    }

    // commit: lane l<32 owns (fi=l>>3, c=l&7); fc = f0*8+l -> coalesced 128B/wave
    {
        float v = 0.0f;
#pragma unroll
        for (int fj = 0; fj < 4; ++fj)
#pragma unroll
            for (int cj = 0; cj < 8; ++cj)
                v = (lane == fj * 8 + cj) ? acc[fj][cj] : v;
        if (lane < 32)
            ws[WS_PSUM + ((size_t)(b * SG + blockIdx.x)) * 128 + f0 * 8 + lane] = v;
        if (wave == 0) {
            float cv = 0.0f;
#pragma unroll
            for (int cj = 0; cj < 8; ++cj)
                cv = (lane == 32 + cj) ? cnt[cj] : cv;
            if (lane >= 32 && lane < 40)
                ws[WS_PCNT + (b * SG + blockIdx.x) * 8 + (lane - 32)] = cv;
        }
    }
}

// 32 blocks (8 fc-groups x 4 batches), 256 threads. Counts computed
// redundantly per block (blocks cannot depend on each other within a kernel).
__global__ void means_kernel(float* __restrict__ ws) {
    __shared__ float scnt_p[32 * 8];
    __shared__ float scnt[8];
    __shared__ float smean[16 * 16];
    const int t = threadIdx.x, g = blockIdx.x, b = blockIdx.y;

    // counts: c = t&7, part = t>>3 covers 32 parts x 8 blks = 256 blocks
    {
        const int c = t & 7, part = t >> 3;
        float s = 0.0f;
#pragma unroll
        for (int i = 0; i < 8; ++i)
            s += ws[WS_PCNT + (b * SG + part * 8 + i) * 8 + c];
        scnt_p[part * 8 + c] = s;
    }
    __syncthreads();
    if (t < 8) {
        float s = 0.0f;
        for (int p = 0; p < 32; ++p) s += scnt_p[p * 8 + t];
        scnt[t] = s;
    }
    __syncthreads();

    // means for fc in [g*16, g*16+16): fcl = t&15, part = t>>4 (16 x 16 blks)
    {
        const int fcl = t & 15, part = t >> 4;
        const int fc = g * 16 + fcl;
        float s = 0.0f;
#pragma unroll
        for (int i = 0; i < 16; ++i)
            s += ws[WS_PSUM + (size_t)(b * SG + part * 16 + i) * 128 + fc];
        smean[part * 16 + fcl] = s;
    }
    __syncthreads();
    if (t < 16) {
        float s = 0.0f;
        for (int p = 0; p < 16; ++p) s += smean[p * 16 + t];
        const int fc = g * 16 + t;
        ws[WS_MEAN + b * 128 + fc] = s / scnt[fc & 7];
    }
    if (g == 0 && t == 0) {
        float iv = 0.0f;
#pragma unroll
        for (int c = 0; c < 8; ++c) iv += 1.0f / scnt[c];
        ws[WS_INV + b] = iv;
    }
}

// Per-block partial of the distance sum; straight-line single iteration.
__global__ __launch_bounds__(256) void dist_kernel(const float* __restrict__ pred,
                                                   const int* __restrict__ tgt,
                                                   const float* __restrict__ ws,
                                                   float* __restrict__ pout) {
    __shared__ float s_means[C * NF];
    __shared__ float s_red[4];
    const int tid = threadIdx.x;
    const int b   = blockIdx.y;
    if (tid < C * NF) s_means[tid] = ws[WS_MEAN + b * 128 + tid];
    const float invs = ws[WS_INV + b];
    __syncthreads();

    const float* predb = pred + (size_t)b * NF * NPIX;
    const int*   tgtb  = tgt  + (size_t)b * NPIX;

    const int base = blockIdx.x * DCHUNK + tid * 4;
    int4 lab = *(const int4*)(tgtb + base);
    float s0 = 0.f, s1 = 0.f, s2 = 0.f, s3 = 0.f;
#pragma unroll
    for (int f = 0; f < NF; ++f) {
        float4 p = *(const float4*)(predb + f * NPIX + base);
        float d0 = s_means[f * C + lab.x] - p.x;
        float d1 = s_means[f * C + lab.y] - p.y;
        float d2 = s_means[f * C + lab.z] - p.z;
        float d3 = s_means[f * C + lab.w] - p.w;
        s0 += d0 * d0; s1 += d1 * d1; s2 += d2 * d2; s3 += d3 * d3;
    }
    float t0 = fminf(fmaxf(sqrtf(s0) - 0.5f, 0.0f), 100000.0f);
    float t1 = fminf(fmaxf(sqrtf(s1) - 0.5f, 0.0f), 100000.0f);
    float t2 = fminf(fmaxf(sqrtf(s2) - 0.5f, 0.0f), 100000.0f);
    float t3 = fminf(fmaxf(sqrtf(s3) - 0.5f, 0.0f), 100000.0f);
    float acc = t0 * t0 + t1 * t1 + t2 * t2 + t3 * t3;

#pragma unroll
    for (int off = 32; off > 0; off >>= 1) acc += __shfl_down(acc, off);
    const int lane = tid & 63, wave = tid >> 6;
    if (lane == 0) s_red[wave] = acc;
    __syncthreads();
    if (tid == 0) {
        float tot = s_red[0] + s_red[1] + s_red[2] + s_red[3];
        pout[b * DG + blockIdx.x] = tot * invs * 0.125f;
    }
}

// One block, 512 threads: sum the 1024 dist partials, plain store to out.
__global__ void final_kernel(const float* __restrict__ pout, float* __restrict__ out) {
    __shared__ float sr[8];
    const int t = threadIdx.x;
    float v = pout[t] + pout[t + 512];
#pragma unroll
    for (int off = 32; off > 0; off >>= 1) v += __shfl_xor(v, off);
    if ((t & 63) == 0) sr[t >> 6] = v;
    __syncthreads();
    if (t == 0) {
        float s = 0.0f;
#pragma unroll
        for (int i = 0; i < 8; ++i) s += sr[i];
        out[0] = s;
    }
}

extern "C" void kernel_launch(void* const* d_in, const int* in_sizes, int n_in,
                              void* d_out, int out_size, void* d_ws, size_t ws_size,
                              hipStream_t stream) {
    const float* pred = (const float*)d_in[0];
    const int*   tgt  = (const int*)d_in[1];
    float* out = (float*)d_out;
    float* ws  = (float*)d_ws;

    sums_kernel<<<dim3(SG, NB), dim3(256), 0, stream>>>(pred, tgt, ws);
    means_kernel<<<dim3(8, NB), dim3(256), 0, stream>>>(ws);
    dist_kernel<<<dim3(DG, NB), dim3(256), 0, stream>>>(pred, tgt, ws, ws + WS_POUT);
    final_kernel<<<dim3(1), dim3(512), 0, stream>>>(ws + WS_POUT, out);
}